// Round 2
// baseline (1580.517 us; speedup 1.0000x reference)
//
#include <hip/hip_runtime.h>
#include <hip/hip_bf16.h>

typedef __bf16 bf16;
typedef bf16 bf16x8 __attribute__((ext_vector_type(8)));
typedef float f32x4 __attribute__((ext_vector_type(4)));

constexpr int NN = 30000;
constexpr int NE = 600000;
constexpr int D  = 128;

__device__ inline f32x4 mfma16(bf16x8 a, bf16x8 b, f32x4 c) {
    return __builtin_amdgcn_mfma_f32_16x16x32_bf16(a, b, c, 0, 0, 0);
}
__device__ inline bf16x8 ld8(const bf16* p) {
    return *reinterpret_cast<const bf16x8*>(p);
}
__device__ inline bf16x8 cvt8(const float* p) {
    float4 v0 = reinterpret_cast<const float4*>(p)[0];
    float4 v1 = reinterpret_cast<const float4*>(p)[1];
    bf16x8 r;
    r[0] = (bf16)v0.x; r[1] = (bf16)v0.y; r[2] = (bf16)v0.z; r[3] = (bf16)v0.w;
    r[4] = (bf16)v1.x; r[5] = (bf16)v1.y; r[6] = (bf16)v1.z; r[7] = (bf16)v1.w;
    return r;
}
__device__ inline int swz512(int row, int byteInRow) {
    return row * 512 + (byteInRow ^ ((row & 15) << 4));
}

// ---------------------------------------------------------------- prep
struct TMat { const float* src; bf16* dst; int K; int Nc; };
struct TPack { TMat m[12]; };

__global__ void transpose_cast_kernel(TPack p) {
    TMat mm = p.m[blockIdx.x];
    int total = mm.K * mm.Nc;
    for (int idx = blockIdx.y * blockDim.x + threadIdx.x; idx < total;
         idx += gridDim.y * blockDim.x) {
        int c = idx / mm.K;
        int k = idx - c * mm.K;
        mm.dst[idx] = (bf16)mm.src[k * mm.Nc + c];
    }
}

// fused W_el2@W_ero and W_el2@W_logit (+ folded biases)
__global__ void fuse_kernel(const float* __restrict__ W_el2,
                            const float* __restrict__ W_ero,
                            const float* __restrict__ W_logit,
                            const float* __restrict__ b_el2,
                            const float* __restrict__ b_ero,
                            const float* __restrict__ b_logit,
                            bf16* __restrict__ W2eroT, bf16* __restrict__ W2lgT,
                            float* __restrict__ b2ero, float* __restrict__ b2lg) {
    int k = blockIdx.x;     // 0..256 (256 = bias row)
    int c = threadIdx.x;
    if (c >= 144) return;
    if (k < 256) {
        if (c < 128) {
            float s = 0.f;
            for (int j = 0; j < 128; ++j) s += W_el2[k * 128 + j] * W_ero[j * 128 + c];
            W2eroT[c * 256 + k] = (bf16)s;
        } else {
            int cc = c - 128;   // 0..15, cols >=2 are zero padding
            float s = 0.f;
            if (cc < 2) for (int j = 0; j < 128; ++j) s += W_el2[k * 128 + j] * W_logit[j * 2 + cc];
            W2lgT[cc * 256 + k] = (bf16)s;
        }
    } else {
        if (c < 128) {
            float s = b_ero[c];
            for (int j = 0; j < 128; ++j) s += 2.f * b_el2[j] * W_ero[j * 128 + c];
            b2ero[c] = s;
        } else if (c < 130) {
            int cc = c - 128;
            float s = b_logit[cc];
            for (int j = 0; j < 128; ++j) s += 2.f * b_el2[j] * W_logit[j * 2 + cc];
            b2lg[cc] = s;
        }
    }
}

// ---------------------------------------------------------------- node-level GEMMs
// O1[r][c] = in[r] @ WT_rows[c]      (+bias, c<256)
// O2[r][c] = in[r] @ WT_rows[256+c]
template<bool IN_BF16>
__global__ void __launch_bounds__(256, 4)
node_pre_kernel(const float* __restrict__ inF, const bf16* __restrict__ inB,
                const bf16* __restrict__ WT,       // [512][128]
                const float* __restrict__ bias0,
                bf16* __restrict__ O1, bf16* __restrict__ O2) {
    const int half = blockIdx.y;
    const int r0 = blockIdx.x * 64;
    const int t = threadIdx.x, wv = t >> 6, l = t & 63, lr = l & 15, qk = l >> 4;
    int row[4];
#pragma unroll
    for (int m = 0; m < 4; ++m) { int r = r0 + m * 16 + lr; row[m] = r < NN ? r : NN - 1; }
    int coln[4];
#pragma unroll
    for (int n = 0; n < 4; ++n) coln[n] = wv * 64 + n * 16 + lr;
    f32x4 acc[4][4];
#pragma unroll
    for (int m = 0; m < 4; ++m)
#pragma unroll
        for (int n = 0; n < 4; ++n) acc[m][n] = 0.f;
#pragma unroll
    for (int ks = 0; ks < 4; ++ks) {
        const int kg = ks * 32 + qk * 8;
        bf16x8 a[4], b[4];
#pragma unroll
        for (int m = 0; m < 4; ++m)
            a[m] = IN_BF16 ? ld8(inB + row[m] * D + kg) : cvt8(inF + row[m] * D + kg);
#pragma unroll
        for (int n = 0; n < 4; ++n) b[n] = ld8(WT + (half * 256 + coln[n]) * 128 + kg);
#pragma unroll
        for (int m = 0; m < 4; ++m)
#pragma unroll
            for (int n = 0; n < 4; ++n) acc[m][n] = mfma16(a[m], b[n], acc[m][n]);
    }
    bf16* O = half ? O2 : O1;
#pragma unroll
    for (int n = 0; n < 4; ++n) {
        float bia = (half == 0 && bias0) ? bias0[coln[n]] : 0.f;
#pragma unroll
        for (int m = 0; m < 4; ++m)
#pragma unroll
            for (int j = 0; j < 4; ++j) {
                int gr = r0 + m * 16 + qk * 4 + j;
                if (gr < NN) O[gr * 256 + coln[n]] = (bf16)(acc[m][n][j] + bia);
            }
    }
}

// S[r][c] += h1[r] @ WtopT[c]
__global__ void __launch_bounds__(256, 4)
s2_update_kernel(const float* __restrict__ h1, const bf16* __restrict__ WtopT,
                 bf16* __restrict__ S) {
    const int r0 = blockIdx.x * 64;
    const int t = threadIdx.x, wv = t >> 6, l = t & 63, lr = l & 15, qk = l >> 4;
    int row[4];
#pragma unroll
    for (int m = 0; m < 4; ++m) { int r = r0 + m * 16 + lr; row[m] = r < NN ? r : NN - 1; }
    int coln[4];
#pragma unroll
    for (int n = 0; n < 4; ++n) coln[n] = wv * 64 + n * 16 + lr;
    f32x4 acc[4][4];
#pragma unroll
    for (int m = 0; m < 4; ++m)
#pragma unroll
        for (int n = 0; n < 4; ++n) acc[m][n] = 0.f;
#pragma unroll
    for (int ks = 0; ks < 4; ++ks) {
        const int kg = ks * 32 + qk * 8;
        bf16x8 a[4], b[4];
#pragma unroll
        for (int m = 0; m < 4; ++m) a[m] = cvt8(h1 + row[m] * D + kg);
#pragma unroll
        for (int n = 0; n < 4; ++n) b[n] = ld8(WtopT + coln[n] * 128 + kg);
#pragma unroll
        for (int m = 0; m < 4; ++m)
#pragma unroll
            for (int n = 0; n < 4; ++n) acc[m][n] = mfma16(a[m], b[n], acc[m][n]);
    }
#pragma unroll
    for (int n = 0; n < 4; ++n)
#pragma unroll
        for (int m = 0; m < 4; ++m)
#pragma unroll
            for (int j = 0; j < 4; ++j) {
                int gr = r0 + m * 16 + qk * 4 + j;
                if (gr < NN) {
                    int idx = gr * 256 + coln[n];
                    S[idx] = (bf16)((float)S[idx] + acc[m][n][j]);
                }
            }
}

// ---------------------------------------------------------------- edge message pass
// edge_feat = relu(S[src]+B[dst]) @ We2T + b_e2 ; h_out[dst] += edge_feat
__global__ void __launch_bounds__(256, 4)
edge_msg_kernel(const bf16* __restrict__ S, const bf16* __restrict__ Bm,
                const int* __restrict__ src, const int* __restrict__ dst,
                const bf16* __restrict__ We2T,   // [128][256]
                const float* __restrict__ b_e2,
                float* __restrict__ h_out) {
    __shared__ int s_src[128];
    __shared__ int s_dst[128];
    const int t = threadIdx.x, wv = t >> 6, l = t & 63, lr = l & 15, qk = l >> 4;
    const int e0 = blockIdx.x * 128;
    if (t < 128)      s_src[t] = src[min(e0 + t, NE - 1)];
    else              s_dst[t - 128] = dst[min(e0 + t - 128, NE - 1)];
    __syncthreads();

    const bf16* pS[2];
    const bf16* pB[2];
#pragma unroll
    for (int m = 0; m < 2; ++m) {
        int el = wv * 32 + m * 16 + lr;
        pS[m] = S + s_src[el] * 256;
        pB[m] = Bm + s_dst[el] * 256;
    }
    f32x4 acc[2][8];
#pragma unroll
    for (int m = 0; m < 2; ++m)
#pragma unroll
        for (int n = 0; n < 8; ++n) acc[m][n] = 0.f;

#pragma unroll
    for (int ks = 0; ks < 8; ++ks) {
        const int kg = ks * 32 + qk * 8;
        bf16x8 a[2];
#pragma unroll
        for (int m = 0; m < 2; ++m) {
            bf16x8 sa = ld8(pS[m] + kg);
            bf16x8 sb = ld8(pB[m] + kg);
#pragma unroll
            for (int i = 0; i < 8; ++i) {
                float f = (float)sa[i] + (float)sb[i];
                a[m][i] = (bf16)(f > 0.f ? f : 0.f);
            }
        }
#pragma unroll
        for (int n = 0; n < 8; ++n) {
            bf16x8 b = ld8(We2T + (n * 16 + lr) * 256 + kg);
#pragma unroll
            for (int m = 0; m < 2; ++m) acc[m][n] = mfma16(a[m], b, acc[m][n]);
        }
    }
#pragma unroll
    for (int n = 0; n < 8; ++n) {
        int col = n * 16 + lr;
        float bia = b_e2[col];
#pragma unroll
        for (int m = 0; m < 2; ++m)
#pragma unroll
            for (int j = 0; j < 4; ++j) {
                int el = wv * 32 + m * 16 + qk * 4 + j;
                if (e0 + el < NE)
                    atomicAdd(h_out + s_dst[el] * D + col, acc[m][n][j] + bia);
            }
    }
}

// ---------------------------------------------------------------- node MLP (nf2 only)
__global__ void __launch_bounds__(256, 2)
node_mlp_kernel(const float* __restrict__ node_feat,
                const float* __restrict__ h2,
                const bf16* __restrict__ Wn1T,   // [256][256]
                const bf16* __restrict__ Wn2T,   // [128][256]
                const float* __restrict__ b_n1,
                const float* __restrict__ b_n2,
                bf16* __restrict__ nf2_bf) {
    __shared__ __align__(16) char sH[64 * 512];
    const int t = threadIdx.x, wv = t >> 6, l = t & 63, lr = l & 15, qk = l >> 4;
    const int r0 = blockIdx.x * 64;
    const float* pN[4];
    const float* pH[4];
#pragma unroll
    for (int m = 0; m < 4; ++m) {
        int r = r0 + m * 16 + lr;
        r = r < NN ? r : NN - 1;
        pN[m] = node_feat + r * D;
        pH[m] = h2 + r * D;
    }
    int coln[4];
#pragma unroll
    for (int n = 0; n < 4; ++n) coln[n] = wv * 64 + n * 16 + lr;
    f32x4 acc[4][4];
#pragma unroll
    for (int m = 0; m < 4; ++m)
#pragma unroll
        for (int n = 0; n < 4; ++n) acc[m][n] = 0.f;
#pragma unroll
    for (int ks = 0; ks < 4; ++ks) {
        const int kg = ks * 32 + qk * 8;
        bf16x8 a[4], b[4];
#pragma unroll
        for (int m = 0; m < 4; ++m) a[m] = cvt8(pN[m] + kg);
#pragma unroll
        for (int n = 0; n < 4; ++n) b[n] = ld8(Wn1T + coln[n] * 256 + kg);
#pragma unroll
        for (int m = 0; m < 4; ++m)
#pragma unroll
            for (int n = 0; n < 4; ++n) acc[m][n] = mfma16(a[m], b[n], acc[m][n]);
#pragma unroll
        for (int m = 0; m < 4; ++m) a[m] = cvt8(pH[m] + kg);
#pragma unroll
        for (int n = 0; n < 4; ++n) b[n] = ld8(Wn1T + coln[n] * 256 + 128 + kg);
#pragma unroll
        for (int m = 0; m < 4; ++m)
#pragma unroll
            for (int n = 0; n < 4; ++n) acc[m][n] = mfma16(a[m], b[n], acc[m][n]);
    }
#pragma unroll
    for (int n = 0; n < 4; ++n) {
        float bia = b_n1[coln[n]];
#pragma unroll
        for (int m = 0; m < 4; ++m)
#pragma unroll
            for (int j = 0; j < 4; ++j) {
                int row = m * 16 + qk * 4 + j;
                float v = acc[m][n][j] + bia;
                v = v > 0.f ? v : 0.f;
                *reinterpret_cast<bf16*>(sH + swz512(row, coln[n] * 2)) = (bf16)v;
            }
    }
    __syncthreads();
    int col2[2];
#pragma unroll
    for (int n = 0; n < 2; ++n) col2[n] = wv * 32 + n * 16 + lr;
    f32x4 acc2[4][2];
#pragma unroll
    for (int m = 0; m < 4; ++m)
#pragma unroll
        for (int n = 0; n < 2; ++n) acc2[m][n] = 0.f;
#pragma unroll
    for (int ks = 0; ks < 8; ++ks) {
        const int k0 = ks * 32 + qk * 8;
        bf16x8 a[4], b[2];
#pragma unroll
        for (int m = 0; m < 4; ++m)
            a[m] = *reinterpret_cast<const bf16x8*>(sH + swz512(m * 16 + lr, k0 * 2));
#pragma unroll
        for (int n = 0; n < 2; ++n) b[n] = ld8(Wn2T + col2[n] * 256 + k0);
#pragma unroll
        for (int m = 0; m < 4; ++m)
#pragma unroll
            for (int n = 0; n < 2; ++n) acc2[m][n] = mfma16(a[m], b[n], acc2[m][n]);
    }
#pragma unroll
    for (int n = 0; n < 2; ++n) {
        float bia = b_n2[col2[n]];
#pragma unroll
        for (int m = 0; m < 4; ++m)
#pragma unroll
            for (int j = 0; j < 4; ++j) {
                int gr = r0 + m * 16 + qk * 4 + j;
                if (gr < NN) nf2_bf[gr * D + col2[n]] = (bf16)(acc2[m][n][j] + bia);
            }
    }
}

// ---------------------------------------------------------------- edge logits (fast)
// H = relu(U[s]+V[d]) + relu(U[d]+V[s]); e_ro = H@W2eroT + b2ero; e_lg = H@W2lgT + b2lg
__global__ void __launch_bounds__(256, 4)
edge_logit_fast(const bf16* __restrict__ U, const bf16* __restrict__ V,
                const int* __restrict__ src, const int* __restrict__ dst,
                const bf16* __restrict__ W2eroT,   // [128][256]
                const bf16* __restrict__ W2lgT,    // [16][256], cols>=2 zero
                const float* __restrict__ b2ero, const float* __restrict__ b2lg,
                float* __restrict__ e_ro, float* __restrict__ e_lg) {
    __shared__ int s_src[128];
    __shared__ int s_dst[128];
    const int t = threadIdx.x, wv = t >> 6, l = t & 63, lr = l & 15, qk = l >> 4;
    const int e0 = blockIdx.x * 128;
    if (t < 128)      s_src[t] = src[min(e0 + t, NE - 1)];
    else              s_dst[t - 128] = dst[min(e0 + t - 128, NE - 1)];
    __syncthreads();

    int is[2], id[2];
#pragma unroll
    for (int m = 0; m < 2; ++m) {
        int el = wv * 32 + m * 16 + lr;
        is[m] = s_src[el];
        id[m] = s_dst[el];
    }
    f32x4 aro[2][8];
    f32x4 alg[2];
#pragma unroll
    for (int m = 0; m < 2; ++m) {
        alg[m] = 0.f;
#pragma unroll
        for (int n = 0; n < 8; ++n) aro[m][n] = 0.f;
    }
#pragma unroll
    for (int ks = 0; ks < 8; ++ks) {
        const int kg = ks * 32 + qk * 8;
        bf16x8 a[2];
#pragma unroll
        for (int m = 0; m < 2; ++m) {
            bf16x8 us = ld8(U + is[m] * 256 + kg);
            bf16x8 vd = ld8(V + id[m] * 256 + kg);
            bf16x8 ud = ld8(U + id[m] * 256 + kg);
            bf16x8 vs = ld8(V + is[m] * 256 + kg);
#pragma unroll
            for (int i = 0; i < 8; ++i) {
                float f1 = (float)us[i] + (float)vd[i]; f1 = f1 > 0.f ? f1 : 0.f;
                float f2 = (float)ud[i] + (float)vs[i]; f2 = f2 > 0.f ? f2 : 0.f;
                a[m][i] = (bf16)(f1 + f2);
            }
        }
#pragma unroll
        for (int n = 0; n < 8; ++n) {
            bf16x8 b = ld8(W2eroT + (n * 16 + lr) * 256 + kg);
#pragma unroll
            for (int m = 0; m < 2; ++m) aro[m][n] = mfma16(a[m], b, aro[m][n]);
        }
        bf16x8 blg = ld8(W2lgT + lr * 256 + kg);
#pragma unroll
        for (int m = 0; m < 2; ++m) alg[m] = mfma16(a[m], blg, alg[m]);
    }
#pragma unroll
    for (int n = 0; n < 8; ++n) {
        int col = n * 16 + lr;
        float bia = b2ero[col];
#pragma unroll
        for (int m = 0; m < 2; ++m)
#pragma unroll
            for (int j = 0; j < 4; ++j) {
                int el = wv * 32 + m * 16 + qk * 4 + j;
                int e = e0 + el;
                if (e < NE) e_ro[e * D + col] = aro[m][n][j] + bia;
            }
    }
    if (lr < 2) {
        float bia = b2lg[lr];
#pragma unroll
        for (int m = 0; m < 2; ++m)
#pragma unroll
            for (int j = 0; j < 4; ++j) {
                int el = wv * 32 + m * 16 + qk * 4 + j;
                int e = e0 + el;
                if (e < NE) e_lg[e * 2 + lr] = alg[m][j] + bia;
            }
    }
}

// ---------------------------------------------------------------- edge logits (fallback, round-1)
__global__ void __launch_bounds__(256, 2)
edge_logit_full(const bf16* __restrict__ nf2_bf,
                const int* __restrict__ src, const int* __restrict__ dst,
                const bf16* __restrict__ Wel1T, const bf16* __restrict__ Wel2T,
                const bf16* __restrict__ WeroT, const float* __restrict__ W_logit,
                const float* __restrict__ b_el1, const float* __restrict__ b_el2,
                const float* __restrict__ b_ero, const float* __restrict__ b_logit,
                float* __restrict__ e_ro, float* __restrict__ e_lg) {
    __shared__ int s_src[64];
    __shared__ int s_dst[64];
    __shared__ __align__(16) char sH[64 * 512];
    const int t = threadIdx.x, wv = t >> 6, l = t & 63, lr = l & 15, qk = l >> 4;
    const int e0 = blockIdx.x * 64;
    if (t < 64)       s_src[t] = src[e0 + t];
    else if (t < 128) s_dst[t - 64] = dst[e0 + (t - 64)];
    __syncthreads();
    const bf16* pS[4];
    const bf16* pD[4];
#pragma unroll
    for (int m = 0; m < 4; ++m) {
        int e = m * 16 + lr;
        pS[m] = nf2_bf + s_src[e] * D;
        pD[m] = nf2_bf + s_dst[e] * D;
    }
    int coln[4];
#pragma unroll
    for (int n = 0; n < 4; ++n) coln[n] = wv * 64 + n * 16 + lr;
    f32x4 h1[4][4], h2[4][4];
#pragma unroll
    for (int m = 0; m < 4; ++m)
#pragma unroll
        for (int n = 0; n < 4; ++n) { h1[m][n] = 0.f; h2[m][n] = 0.f; }
#pragma unroll
    for (int ks = 0; ks < 4; ++ks) {
        const int kg = ks * 32 + qk * 8;
        bf16x8 as[4], ad[4];
#pragma unroll
        for (int m = 0; m < 4; ++m) { as[m] = ld8(pS[m] + kg); ad[m] = ld8(pD[m] + kg); }
#pragma unroll
        for (int n = 0; n < 4; ++n) {
            bf16x8 bt = ld8(Wel1T + coln[n] * 256 + kg);
            bf16x8 bb = ld8(Wel1T + coln[n] * 256 + 128 + kg);
#pragma unroll
            for (int m = 0; m < 4; ++m) {
                h1[m][n] = mfma16(as[m], bt, h1[m][n]);
                h1[m][n] = mfma16(ad[m], bb, h1[m][n]);
                h2[m][n] = mfma16(ad[m], bt, h2[m][n]);
                h2[m][n] = mfma16(as[m], bb, h2[m][n]);
            }
        }
    }
#pragma unroll
    for (int n = 0; n < 4; ++n) {
        float bia = b_el1[coln[n]];
#pragma unroll
        for (int m = 0; m < 4; ++m)
#pragma unroll
            for (int j = 0; j < 4; ++j) {
                int row = m * 16 + qk * 4 + j;
                float v1 = h1[m][n][j] + bia; v1 = v1 > 0.f ? v1 : 0.f;
                float v2 = h2[m][n][j] + bia; v2 = v2 > 0.f ? v2 : 0.f;
                *reinterpret_cast<bf16*>(sH + swz512(row, coln[n] * 2)) = (bf16)(v1 + v2);
            }
    }
    __syncthreads();
    int col2[2];
#pragma unroll
    for (int n = 0; n < 2; ++n) col2[n] = wv * 32 + n * 16 + lr;
    f32x4 acc2[4][2];
#pragma unroll
    for (int m = 0; m < 4; ++m)
#pragma unroll
        for (int n = 0; n < 2; ++n) acc2[m][n] = 0.f;
#pragma unroll
    for (int ks = 0; ks < 8; ++ks) {
        const int k0 = ks * 32 + qk * 8;
        bf16x8 a[4], b[2];
#pragma unroll
        for (int m = 0; m < 4; ++m)
            a[m] = *reinterpret_cast<const bf16x8*>(sH + swz512(m * 16 + lr, k0 * 2));
#pragma unroll
        for (int n = 0; n < 2; ++n) b[n] = ld8(Wel2T + col2[n] * 256 + k0);
#pragma unroll
        for (int m = 0; m < 4; ++m)
#pragma unroll
            for (int n = 0; n < 2; ++n) acc2[m][n] = mfma16(a[m], b[n], acc2[m][n]);
    }
    __syncthreads();
    // comb -> LDS overlay [64][128] bf16 (linear, conflicts acceptable in fallback)
#pragma unroll
    for (int n = 0; n < 2; ++n) {
        float bia = 2.f * b_el2[col2[n]];
#pragma unroll
        for (int m = 0; m < 4; ++m)
#pragma unroll
            for (int j = 0; j < 4; ++j) {
                int row = m * 16 + qk * 4 + j;
                *reinterpret_cast<bf16*>(sH + row * 256 + ((col2[n] * 2) ^ ((row & 15) << 4)))
                    = (bf16)(acc2[m][n][j] + bia);
            }
    }
    __syncthreads();
    f32x4 acc3[4][2];
#pragma unroll
    for (int m = 0; m < 4; ++m)
#pragma unroll
        for (int n = 0; n < 2; ++n) acc3[m][n] = 0.f;
#pragma unroll
    for (int ks = 0; ks < 4; ++ks) {
        const int k0 = ks * 32 + qk * 8;
        bf16x8 a[4], b[2];
#pragma unroll
        for (int m = 0; m < 4; ++m) {
            int row = m * 16 + lr;
            a[m] = *reinterpret_cast<const bf16x8*>(sH + row * 256 + ((k0 * 2) ^ ((row & 15) << 4)));
        }
#pragma unroll
        for (int n = 0; n < 2; ++n) b[n] = ld8(WeroT + col2[n] * D + k0);
#pragma unroll
        for (int m = 0; m < 4; ++m)
#pragma unroll
            for (int n = 0; n < 2; ++n) acc3[m][n] = mfma16(a[m], b[n], acc3[m][n]);
    }
#pragma unroll
    for (int n = 0; n < 2; ++n) {
        float bia = b_ero[col2[n]];
#pragma unroll
        for (int m = 0; m < 4; ++m)
#pragma unroll
            for (int j = 0; j < 4; ++j) {
                int e = e0 + m * 16 + qk * 4 + j;
                e_ro[e * D + col2[n]] = acc3[m][n][j] + bia;
            }
    }
    if (t < 128) {
        int el = t >> 1;
        int c = t & 1;
        float s = 0.f;
#pragma unroll 8
        for (int k = 0; k < D; ++k) {
            float cv = (float)*reinterpret_cast<const bf16*>(
                sH + el * 256 + ((k * 2) ^ ((el & 15) << 4)));
            s += cv * W_logit[k * 2 + c];
        }
        e_lg[(e0 + el) * 2 + c] = s + b_logit[c];
    }
}

// ---------------------------------------------------------------- n_out readout
__global__ void __launch_bounds__(256, 4)
nro_kernel(const bf16* __restrict__ nf2_bf, const bf16* __restrict__ WnroT,
           const float* __restrict__ b_nro, float* __restrict__ n_out) {
    const int r0 = blockIdx.x * 64;
    const int t = threadIdx.x, wv = t >> 6, l = t & 63, lr = l & 15, qk = l >> 4;
    int row[4];
#pragma unroll
    for (int m = 0; m < 4; ++m) { int r = r0 + m * 16 + lr; row[m] = r < NN ? r : NN - 1; }
    int col2[2];
#pragma unroll
    for (int n = 0; n < 2; ++n) col2[n] = wv * 32 + n * 16 + lr;
    f32x4 acc[4][2];
#pragma unroll
    for (int m = 0; m < 4; ++m)
#pragma unroll
        for (int n = 0; n < 2; ++n) acc[m][n] = 0.f;
#pragma unroll
    for (int ks = 0; ks < 4; ++ks) {
        const int kg = ks * 32 + qk * 8;
        bf16x8 a[4], b[2];
#pragma unroll
        for (int m = 0; m < 4; ++m) a[m] = ld8(nf2_bf + row[m] * D + kg);
#pragma unroll
        for (int n = 0; n < 2; ++n) b[n] = ld8(WnroT + col2[n] * 128 + kg);
#pragma unroll
        for (int m = 0; m < 4; ++m)
#pragma unroll
            for (int n = 0; n < 2; ++n) acc[m][n] = mfma16(a[m], b[n], acc[m][n]);
    }
#pragma unroll
    for (int n = 0; n < 2; ++n) {
        float bia = b_nro[col2[n]];
#pragma unroll
        for (int m = 0; m < 4; ++m)
#pragma unroll
            for (int j = 0; j < 4; ++j) {
                int gr = r0 + m * 16 + qk * 4 + j;
                if (gr < NN) n_out[gr * D + col2[n]] = acc[m][n][j] + bia;
            }
    }
}

// ---------------------------------------------------------------- launch
extern "C" void kernel_launch(void* const* d_in, const int* in_sizes, int n_in,
                              void* d_out, int out_size, void* d_ws, size_t ws_size,
                              hipStream_t stream) {
    const float* node_feat = (const float*)d_in[0];
    const int*   src   = (const int*)d_in[1];
    const int*   dst   = (const int*)d_in[2];
    const float* W_e1  = (const float*)d_in[3];
    const float* b_e1  = (const float*)d_in[4];
    const float* W_e2  = (const float*)d_in[5];
    const float* b_e2  = (const float*)d_in[6];
    const float* W_n1  = (const float*)d_in[7];
    const float* b_n1  = (const float*)d_in[8];
    const float* W_n2  = (const float*)d_in[9];
    const float* b_n2  = (const float*)d_in[10];
    const float* W_el1 = (const float*)d_in[11];
    const float* b_el1 = (const float*)d_in[12];
    const float* W_el2 = (const float*)d_in[13];
    const float* b_el2 = (const float*)d_in[14];
    const float* W_logit = (const float*)d_in[15];
    const float* b_logit = (const float*)d_in[16];
    const float* W_nro = (const float*)d_in[17];
    const float* b_nro = (const float*)d_in[18];
    const float* W_ero = (const float*)d_in[19];
    const float* b_ero = (const float*)d_in[20];

    char* ws = (char*)d_ws;
    bf16* wb = (bf16*)ws;
    bf16* WmbT   = wb;            // [512][128]
    bf16* WtopT  = wb + 65536;    // [256][128]
    bf16* We2T   = wb + 98304;    // [128][256]
    bf16* Wn1T   = wb + 131072;   // [256][256]
    bf16* Wn2T   = wb + 196608;   // [128][256]
    bf16* WuvT   = wb + 229376;   // [512][128]
    bf16* WnroT  = wb + 294912;   // [128][128]
    bf16* W2eroT = wb + 311296;   // [128][256]
    bf16* W2lgT  = wb + 344064;   // [16][256]
    bf16* Wel1T  = wb + 348160;   // [256][256]
    bf16* Wel2T  = wb + 413696;   // [128][256]
    bf16* WeroT  = wb + 446464;   // [128][128]
    float* fb    = (float*)(ws + 928000);
    float* b2ero = fb;            // 128
    float* b2lg  = fb + 128;      // 2
    bf16* nf2_bf = (bf16*)(ws + 1048576);        // 7.68 MB
    bf16* Vbuf   = (bf16*)(ws + 9000000);        // 15.36 MB (needs big ws)
    const bool big_ws = ws_size >= (size_t)24360000;

    float* out   = (float*)d_out;
    float* n_out = out;                 // NN*128 f32
    float* e_ro  = out + 3840000;       // NE*128 f32
    float* e_lg  = out + 80640000;      // NE*2 f32
    // d_out-region scratch overlays (lifetimes verified against launch order):
    float* h1 = n_out;                               // pass-1 accumulation
    bf16*  S  = (bf16*)e_ro;                         // 15.36 MB
    bf16*  Bm = (bf16*)((char*)e_ro + 15360000);     // 15.36 MB
    float* h2 = (float*)((char*)e_ro + 30720000);    // 15.36 MB
    bf16*  U  = (bf16*)n_out;                        // after h1 dead

    TPack pk;
    pk.m[0]  = {W_e1 + 128 * 256, WmbT,              128, 256};
    pk.m[1]  = {W_e1 + 256 * 256, WmbT + 256 * 128,  128, 256};
    pk.m[2]  = {W_e1,             WtopT,             128, 256};
    pk.m[3]  = {W_e2,             We2T,              256, 128};
    pk.m[4]  = {W_n1,             Wn1T,              256, 256};
    pk.m[5]  = {W_n2,             Wn2T,              256, 128};
    pk.m[6]  = {W_el1,            WuvT,              128, 256};
    pk.m[7]  = {W_el1 + 128 * 256, WuvT + 256 * 128, 128, 256};
    pk.m[8]  = {W_nro,            WnroT,             128, 128};
    pk.m[9]  = {W_el1,            Wel1T,             256, 256};
    pk.m[10] = {W_el2,            Wel2T,             256, 128};
    pk.m[11] = {W_ero,            WeroT,             128, 128};
    transpose_cast_kernel<<<dim3(12, 40), 256, 0, stream>>>(pk);
    fuse_kernel<<<257, 160, 0, stream>>>(W_el2, W_ero, W_logit, b_el2, b_ero, b_logit,
                                         W2eroT, W2lgT, b2ero, b2lg);
    hipMemsetAsync(h1, 0, (size_t)NN * D * 4, stream);
    hipMemsetAsync(h2, 0, (size_t)NN * D * 4, stream);

    // S = nf@W_e1[128:256]+b_e1 ; B = nf@W_e1[256:384]
    node_pre_kernel<false><<<dim3(469, 2), 256, 0, stream>>>(
        node_feat, nullptr, WmbT, b_e1, S, Bm);
    // pass 1 (h=0): h1 = scatter-sum(relu(S+B)@We2+b)
    edge_msg_kernel<<<4688, 256, 0, stream>>>(S, Bm, src, dst, We2T, b_e2, h1);
    // S += h1@W_e1[0:128]
    s2_update_kernel<<<469, 256, 0, stream>>>(h1, WtopT, S);
    // pass 2
    edge_msg_kernel<<<4688, 256, 0, stream>>>(S, Bm, src, dst, We2T, b_e2, h2);
    // nf2
    node_mlp_kernel<<<469, 256, 0, stream>>>(node_feat, h2, Wn1T, Wn2T, b_n1, b_n2, nf2_bf);

    if (big_ws) {
        node_pre_kernel<true><<<dim3(469, 2), 256, 0, stream>>>(
            nullptr, nf2_bf, WuvT, b_el1, U, Vbuf);
        edge_logit_fast<<<4688, 256, 0, stream>>>(
            U, Vbuf, src, dst, W2eroT, W2lgT, b2ero, b2lg, e_ro, e_lg);
    } else {
        edge_logit_full<<<9375, 256, 0, stream>>>(
            nf2_bf, src, dst, Wel1T, Wel2T, WeroT, W_logit,
            b_el1, b_el2, b_ero, b_logit, e_ro, e_lg);
    }
    nro_kernel<<<469, 256, 0, stream>>>(nf2_bf, WnroT, b_nro, n_out);
}

// Round 3
// 782.652 us; speedup vs baseline: 2.0194x; 2.0194x over previous
//
#include <hip/hip_runtime.h>
#include <hip/hip_bf16.h>

typedef __bf16 bf16;
typedef unsigned short u16;
typedef bf16 bf16x8 __attribute__((ext_vector_type(8)));
typedef bf16 bf16x4 __attribute__((ext_vector_type(4)));
typedef float f32x4 __attribute__((ext_vector_type(4)));

constexpr int NN = 30000;
constexpr int NE = 600000;
constexpr int D  = 128;

__device__ inline f32x4 mfma16(bf16x8 a, bf16x8 b, f32x4 c) {
    return __builtin_amdgcn_mfma_f32_16x16x32_bf16(a, b, c, 0, 0, 0);
}
__device__ inline bf16x8 ld8(const bf16* p) {
    return *reinterpret_cast<const bf16x8*>(p);
}
__device__ inline bf16x8 cvt8(const float* p) {
    float4 v0 = reinterpret_cast<const float4*>(p)[0];
    float4 v1 = reinterpret_cast<const float4*>(p)[1];
    bf16x8 r;
    r[0] = (bf16)v0.x; r[1] = (bf16)v0.y; r[2] = (bf16)v0.z; r[3] = (bf16)v0.w;
    r[4] = (bf16)v1.x; r[5] = (bf16)v1.y; r[6] = (bf16)v1.z; r[7] = (bf16)v1.w;
    return r;
}
__device__ inline int swz512(int row, int byteInRow) {
    return row * 512 + (byteInRow ^ ((row & 15) << 4));
}

// ---------------------------------------------------------------- prep
struct TMat { const float* src; bf16* dst; int K; int Nc; };
struct TPack { TMat m[12]; };

__global__ void transpose_cast_kernel(TPack p) {
    TMat mm = p.m[blockIdx.x];
    int total = mm.K * mm.Nc;
    for (int idx = blockIdx.y * blockDim.x + threadIdx.x; idx < total;
         idx += gridDim.y * blockDim.x) {
        int c = idx / mm.K;
        int k = idx - c * mm.K;
        mm.dst[idx] = (bf16)mm.src[k * mm.Nc + c];
    }
}

__global__ void fuse_kernel(const float* __restrict__ W_el2,
                            const float* __restrict__ W_ero,
                            const float* __restrict__ W_logit,
                            const float* __restrict__ b_el2,
                            const float* __restrict__ b_ero,
                            const float* __restrict__ b_logit,
                            bf16* __restrict__ W2eroT, bf16* __restrict__ W2lgT,
                            float* __restrict__ b2ero, float* __restrict__ b2lg) {
    int k = blockIdx.x;
    int c = threadIdx.x;
    if (c >= 144) return;
    if (k < 256) {
        if (c < 128) {
            float s = 0.f;
            for (int j = 0; j < 128; ++j) s += W_el2[k * 128 + j] * W_ero[j * 128 + c];
            W2eroT[c * 256 + k] = (bf16)s;
        } else {
            int cc = c - 128;
            float s = 0.f;
            if (cc < 2) for (int j = 0; j < 128; ++j) s += W_el2[k * 128 + j] * W_logit[j * 2 + cc];
            W2lgT[cc * 256 + k] = (bf16)s;
        }
    } else {
        if (c < 128) {
            float s = b_ero[c];
            for (int j = 0; j < 128; ++j) s += 2.f * b_el2[j] * W_ero[j * 128 + c];
            b2ero[c] = s;
        } else if (c < 130) {
            int cc = c - 128;
            float s = b_logit[cc];
            for (int j = 0; j < 128; ++j) s += 2.f * b_el2[j] * W_logit[j * 2 + cc];
            b2lg[cc] = s;
        }
    }
}

// ---------------------------------------------------------------- sort (counting sort by dst)
__global__ void hist_kernel(const int* __restrict__ dst, int* __restrict__ counts) {
    int e = blockIdx.x * blockDim.x + threadIdx.x;
    if (e < NE) atomicAdd(counts + dst[e], 1);
}

__global__ void scan_kernel(const int* __restrict__ counts, int* __restrict__ offsets,
                            int* __restrict__ cursor) {
    __shared__ int tmp[1024];
    __shared__ int base;
    if (threadIdx.x == 0) base = 0;
    __syncthreads();
    for (int c = 0; c < NN; c += 1024) {
        int i = c + threadIdx.x;
        int v = (i < NN) ? counts[i] : 0;
        tmp[threadIdx.x] = v;
        __syncthreads();
        for (int off = 1; off < 1024; off <<= 1) {
            int x = (threadIdx.x >= off) ? tmp[threadIdx.x - off] : 0;
            __syncthreads();
            tmp[threadIdx.x] += x;
            __syncthreads();
        }
        if (i < NN) {
            int excl = base + tmp[threadIdx.x] - v;
            offsets[i] = excl;
            cursor[i] = excl;
        }
        __syncthreads();
        if (threadIdx.x == 0) base += tmp[1023];
        __syncthreads();
    }
    if (threadIdx.x == 0) offsets[NN] = NE;
}

__global__ void scatter_kernel(const int* __restrict__ src, const int* __restrict__ dst,
                               int* __restrict__ cursor, int* __restrict__ perm,
                               u16* __restrict__ srcS, u16* __restrict__ dstS) {
    int e = blockIdx.x * blockDim.x + threadIdx.x;
    if (e < NE) {
        int d = dst[e];
        int p = atomicAdd(cursor + d, 1);
        perm[p] = e;
        srcS[p] = (u16)src[e];
        dstS[p] = (u16)d;
    }
}

// ---------------------------------------------------------------- node-level GEMMs
template<bool IN_BF16>
__global__ void __launch_bounds__(256, 4)
node_pre_kernel(const float* __restrict__ inF, const bf16* __restrict__ inB,
                const bf16* __restrict__ WT,       // [512][128]
                const float* __restrict__ bias0,
                bf16* __restrict__ O1, bf16* __restrict__ O2) {
    const int half = blockIdx.y;
    const int r0 = blockIdx.x * 64;
    const int t = threadIdx.x, wv = t >> 6, l = t & 63, lr = l & 15, qk = l >> 4;
    int row[4];
#pragma unroll
    for (int m = 0; m < 4; ++m) { int r = r0 + m * 16 + lr; row[m] = r < NN ? r : NN - 1; }
    int coln[4];
#pragma unroll
    for (int n = 0; n < 4; ++n) coln[n] = wv * 64 + n * 16 + lr;
    f32x4 acc[4][4];
#pragma unroll
    for (int m = 0; m < 4; ++m)
#pragma unroll
        for (int n = 0; n < 4; ++n) acc[m][n] = 0.f;
#pragma unroll
    for (int ks = 0; ks < 4; ++ks) {
        const int kg = ks * 32 + qk * 8;
        bf16x8 a[4], b[4];
#pragma unroll
        for (int m = 0; m < 4; ++m)
            a[m] = IN_BF16 ? ld8(inB + row[m] * D + kg) : cvt8(inF + row[m] * D + kg);
#pragma unroll
        for (int n = 0; n < 4; ++n) b[n] = ld8(WT + (half * 256 + coln[n]) * 128 + kg);
#pragma unroll
        for (int m = 0; m < 4; ++m)
#pragma unroll
            for (int n = 0; n < 4; ++n) acc[m][n] = mfma16(a[m], b[n], acc[m][n]);
    }
    bf16* O = half ? O2 : O1;
#pragma unroll
    for (int n = 0; n < 4; ++n) {
        float bia = (half == 0 && bias0) ? bias0[coln[n]] : 0.f;
#pragma unroll
        for (int m = 0; m < 4; ++m)
#pragma unroll
            for (int j = 0; j < 4; ++j) {
                int gr = r0 + m * 16 + qk * 4 + j;
                if (gr < NN) O[gr * 256 + coln[n]] = (bf16)(acc[m][n][j] + bia);
            }
    }
}

// S[r][c] += h1[r] @ WtopT[c]
template<bool HBF>
__global__ void __launch_bounds__(256, 4)
s2_update_kernel(const void* __restrict__ h1, const bf16* __restrict__ WtopT,
                 bf16* __restrict__ S) {
    const int r0 = blockIdx.x * 64;
    const int t = threadIdx.x, wv = t >> 6, l = t & 63, lr = l & 15, qk = l >> 4;
    int row[4];
#pragma unroll
    for (int m = 0; m < 4; ++m) { int r = r0 + m * 16 + lr; row[m] = r < NN ? r : NN - 1; }
    int coln[4];
#pragma unroll
    for (int n = 0; n < 4; ++n) coln[n] = wv * 64 + n * 16 + lr;
    f32x4 acc[4][4];
#pragma unroll
    for (int m = 0; m < 4; ++m)
#pragma unroll
        for (int n = 0; n < 4; ++n) acc[m][n] = 0.f;
#pragma unroll
    for (int ks = 0; ks < 4; ++ks) {
        const int kg = ks * 32 + qk * 8;
        bf16x8 a[4], b[4];
#pragma unroll
        for (int m = 0; m < 4; ++m) {
            if constexpr (HBF) a[m] = ld8((const bf16*)h1 + row[m] * D + kg);
            else               a[m] = cvt8((const float*)h1 + row[m] * D + kg);
        }
#pragma unroll
        for (int n = 0; n < 4; ++n) b[n] = ld8(WtopT + coln[n] * 128 + kg);
#pragma unroll
        for (int m = 0; m < 4; ++m)
#pragma unroll
            for (int n = 0; n < 4; ++n) acc[m][n] = mfma16(a[m], b[n], acc[m][n]);
    }
#pragma unroll
    for (int n = 0; n < 4; ++n)
#pragma unroll
        for (int m = 0; m < 4; ++m)
#pragma unroll
            for (int j = 0; j < 4; ++j) {
                int gr = r0 + m * 16 + qk * 4 + j;
                if (gr < NN) {
                    int idx = gr * 256 + coln[n];
                    S[idx] = (bf16)((float)S[idx] + acc[m][n][j]);
                }
            }
}

// ---------------------------------------------------------------- segment sum (one wave per dst)
__global__ void __launch_bounds__(256, 8)
seg_sum_kernel(const bf16* __restrict__ S, const bf16* __restrict__ Bm,
               const int* __restrict__ offsets, const u16* __restrict__ srcS,
               bf16* __restrict__ T) {
    const int gw = (blockIdx.x * blockDim.x + threadIdx.x) >> 6;
    if (gw >= NN) return;
    const int l = threadIdx.x & 63;
    const int beg = offsets[gw], end = offsets[gw + 1];
    bf16x4 bv = *reinterpret_cast<const bf16x4*>(Bm + (size_t)gw * 256 + l * 4);
    const float b0 = (float)bv[0], b1 = (float)bv[1], b2 = (float)bv[2], b3 = (float)bv[3];
    float t0 = 0.f, t1 = 0.f, t2 = 0.f, t3 = 0.f;
    int i = beg;
    for (; i + 2 <= end; i += 2) {
        int s0 = srcS[i];
        int s1 = srcS[i + 1];
        bf16x4 a0 = *reinterpret_cast<const bf16x4*>(S + (size_t)s0 * 256 + l * 4);
        bf16x4 a1 = *reinterpret_cast<const bf16x4*>(S + (size_t)s1 * 256 + l * 4);
        float v;
        v = (float)a0[0] + b0; t0 += v > 0.f ? v : 0.f;
        v = (float)a0[1] + b1; t1 += v > 0.f ? v : 0.f;
        v = (float)a0[2] + b2; t2 += v > 0.f ? v : 0.f;
        v = (float)a0[3] + b3; t3 += v > 0.f ? v : 0.f;
        v = (float)a1[0] + b0; t0 += v > 0.f ? v : 0.f;
        v = (float)a1[1] + b1; t1 += v > 0.f ? v : 0.f;
        v = (float)a1[2] + b2; t2 += v > 0.f ? v : 0.f;
        v = (float)a1[3] + b3; t3 += v > 0.f ? v : 0.f;
    }
    if (i < end) {
        int s0 = srcS[i];
        bf16x4 a0 = *reinterpret_cast<const bf16x4*>(S + (size_t)s0 * 256 + l * 4);
        float v;
        v = (float)a0[0] + b0; t0 += v > 0.f ? v : 0.f;
        v = (float)a0[1] + b1; t1 += v > 0.f ? v : 0.f;
        v = (float)a0[2] + b2; t2 += v > 0.f ? v : 0.f;
        v = (float)a0[3] + b3; t3 += v > 0.f ? v : 0.f;
    }
    bf16x4 o;
    o[0] = (bf16)t0; o[1] = (bf16)t1; o[2] = (bf16)t2; o[3] = (bf16)t3;
    *reinterpret_cast<bf16x4*>(T + (size_t)gw * 256 + l * 4) = o;
}

// h[r] = T[r] @ We2T + deg[r]*b_e2   (bf16 out)
__global__ void __launch_bounds__(256, 4)
h_gemm_kernel(const bf16* __restrict__ T, const bf16* __restrict__ We2T,
              const float* __restrict__ b_e2, const int* __restrict__ deg,
              bf16* __restrict__ h) {
    const int r0 = blockIdx.x * 64;
    const int t = threadIdx.x, wv = t >> 6, l = t & 63, lr = l & 15, qk = l >> 4;
    int row[4];
#pragma unroll
    for (int m = 0; m < 4; ++m) { int r = r0 + m * 16 + lr; row[m] = r < NN ? r : NN - 1; }
    int col2[2];
#pragma unroll
    for (int n = 0; n < 2; ++n) col2[n] = wv * 32 + n * 16 + lr;
    f32x4 acc[4][2];
#pragma unroll
    for (int m = 0; m < 4; ++m)
#pragma unroll
        for (int n = 0; n < 2; ++n) acc[m][n] = 0.f;
#pragma unroll
    for (int ks = 0; ks < 8; ++ks) {
        const int kg = ks * 32 + qk * 8;
        bf16x8 a[4], b[2];
#pragma unroll
        for (int m = 0; m < 4; ++m) a[m] = ld8(T + (size_t)row[m] * 256 + kg);
#pragma unroll
        for (int n = 0; n < 2; ++n) b[n] = ld8(We2T + col2[n] * 256 + kg);
#pragma unroll
        for (int m = 0; m < 4; ++m)
#pragma unroll
            for (int n = 0; n < 2; ++n) acc[m][n] = mfma16(a[m], b[n], acc[m][n]);
    }
#pragma unroll
    for (int n = 0; n < 2; ++n) {
        float bw = b_e2[col2[n]];
#pragma unroll
        for (int m = 0; m < 4; ++m)
#pragma unroll
            for (int j = 0; j < 4; ++j) {
                int gr = r0 + m * 16 + qk * 4 + j;
                if (gr < NN)
                    h[(size_t)gr * D + col2[n]] = (bf16)(acc[m][n][j] + (float)deg[gr] * bw);
            }
    }
}

// ---------------------------------------------------------------- node MLP (nf2 only)
template<bool HBF>
__global__ void __launch_bounds__(256, 2)
node_mlp_kernel(const float* __restrict__ node_feat,
                const void* __restrict__ h2,
                const bf16* __restrict__ Wn1T,
                const bf16* __restrict__ Wn2T,
                const float* __restrict__ b_n1,
                const float* __restrict__ b_n2,
                bf16* __restrict__ nf2_bf) {
    __shared__ __align__(16) char sH[64 * 512];
    const int t = threadIdx.x, wv = t >> 6, l = t & 63, lr = l & 15, qk = l >> 4;
    const int r0 = blockIdx.x * 64;
    int row[4];
#pragma unroll
    for (int m = 0; m < 4; ++m) { int r = r0 + m * 16 + lr; row[m] = r < NN ? r : NN - 1; }
    int coln[4];
#pragma unroll
    for (int n = 0; n < 4; ++n) coln[n] = wv * 64 + n * 16 + lr;
    f32x4 acc[4][4];
#pragma unroll
    for (int m = 0; m < 4; ++m)
#pragma unroll
        for (int n = 0; n < 4; ++n) acc[m][n] = 0.f;
#pragma unroll
    for (int ks = 0; ks < 4; ++ks) {
        const int kg = ks * 32 + qk * 8;
        bf16x8 a[4], b[4];
#pragma unroll
        for (int m = 0; m < 4; ++m) a[m] = cvt8(node_feat + (size_t)row[m] * D + kg);
#pragma unroll
        for (int n = 0; n < 4; ++n) b[n] = ld8(Wn1T + coln[n] * 256 + kg);
#pragma unroll
        for (int m = 0; m < 4; ++m)
#pragma unroll
            for (int n = 0; n < 4; ++n) acc[m][n] = mfma16(a[m], b[n], acc[m][n]);
#pragma unroll
        for (int m = 0; m < 4; ++m) {
            if constexpr (HBF) a[m] = ld8((const bf16*)h2 + (size_t)row[m] * D + kg);
            else               a[m] = cvt8((const float*)h2 + (size_t)row[m] * D + kg);
        }
#pragma unroll
        for (int n = 0; n < 4; ++n) b[n] = ld8(Wn1T + coln[n] * 256 + 128 + kg);
#pragma unroll
        for (int m = 0; m < 4; ++m)
#pragma unroll
            for (int n = 0; n < 4; ++n) acc[m][n] = mfma16(a[m], b[n], acc[m][n]);
    }
#pragma unroll
    for (int n = 0; n < 4; ++n) {
        float bia = b_n1[coln[n]];
#pragma unroll
        for (int m = 0; m < 4; ++m)
#pragma unroll
            for (int j = 0; j < 4; ++j) {
                int r = m * 16 + qk * 4 + j;
                float v = acc[m][n][j] + bia;
                v = v > 0.f ? v : 0.f;
                *reinterpret_cast<bf16*>(sH + swz512(r, coln[n] * 2)) = (bf16)v;
            }
    }
    __syncthreads();
    int col2[2];
#pragma unroll
    for (int n = 0; n < 2; ++n) col2[n] = wv * 32 + n * 16 + lr;
    f32x4 acc2[4][2];
#pragma unroll
    for (int m = 0; m < 4; ++m)
#pragma unroll
        for (int n = 0; n < 2; ++n) acc2[m][n] = 0.f;
#pragma unroll
    for (int ks = 0; ks < 8; ++ks) {
        const int k0 = ks * 32 + qk * 8;
        bf16x8 a[4], b[2];
#pragma unroll
        for (int m = 0; m < 4; ++m)
            a[m] = *reinterpret_cast<const bf16x8*>(sH + swz512(m * 16 + lr, k0 * 2));
#pragma unroll
        for (int n = 0; n < 2; ++n) b[n] = ld8(Wn2T + col2[n] * 256 + k0);
#pragma unroll
        for (int m = 0; m < 4; ++m)
#pragma unroll
            for (int n = 0; n < 2; ++n) acc2[m][n] = mfma16(a[m], b[n], acc2[m][n]);
    }
#pragma unroll
    for (int n = 0; n < 2; ++n) {
        float bia = b_n2[col2[n]];
#pragma unroll
        for (int m = 0; m < 4; ++m)
#pragma unroll
            for (int j = 0; j < 4; ++j) {
                int gr = r0 + m * 16 + qk * 4 + j;
                if (gr < NN) nf2_bf[(size_t)gr * D + col2[n]] = (bf16)(acc2[m][n][j] + bia);
            }
    }
}

// ---------------------------------------------------------------- edge logits (dst-sorted)
__global__ void __launch_bounds__(256, 4)
edge_logit_sorted(const bf16* __restrict__ U, const bf16* __restrict__ V,
                  const int* __restrict__ perm, const u16* __restrict__ srcS,
                  const u16* __restrict__ dstS,
                  const bf16* __restrict__ W2eroT, const bf16* __restrict__ W2lgT,
                  const float* __restrict__ b2ero, const float* __restrict__ b2lg,
                  float* __restrict__ e_ro, float* __restrict__ e_lg) {
    __shared__ int s_e[128];
    __shared__ int s_s[128];
    __shared__ int s_d[128];
    const int t = threadIdx.x, wv = t >> 6, l = t & 63, lr = l & 15, qk = l >> 4;
    const int p0 = blockIdx.x * 128;
    if (t < 128) {
        int p = min(p0 + t, NE - 1);
        s_e[t] = perm[p];
        s_s[t] = (int)srcS[p];
        s_d[t] = (int)dstS[p];
    }
    __syncthreads();

    int is[2], id[2];
#pragma unroll
    for (int m = 0; m < 2; ++m) {
        int el = wv * 32 + m * 16 + lr;
        is[m] = s_s[el];
        id[m] = s_d[el];
    }
    f32x4 aro[2][8];
    f32x4 alg[2];
#pragma unroll
    for (int m = 0; m < 2; ++m) {
        alg[m] = 0.f;
#pragma unroll
        for (int n = 0; n < 8; ++n) aro[m][n] = 0.f;
    }
#pragma unroll
    for (int ks = 0; ks < 8; ++ks) {
        const int kg = ks * 32 + qk * 8;
        bf16x8 a[2];
#pragma unroll
        for (int m = 0; m < 2; ++m) {
            bf16x8 us = ld8(U + (size_t)is[m] * 256 + kg);
            bf16x8 vd = ld8(V + (size_t)id[m] * 256 + kg);
            bf16x8 ud = ld8(U + (size_t)id[m] * 256 + kg);
            bf16x8 vs = ld8(V + (size_t)is[m] * 256 + kg);
#pragma unroll
            for (int i = 0; i < 8; ++i) {
                float f1 = (float)us[i] + (float)vd[i]; f1 = f1 > 0.f ? f1 : 0.f;
                float f2 = (float)ud[i] + (float)vs[i]; f2 = f2 > 0.f ? f2 : 0.f;
                a[m][i] = (bf16)(f1 + f2);
            }
        }
#pragma unroll
        for (int n = 0; n < 8; ++n) {
            bf16x8 b = ld8(W2eroT + (n * 16 + lr) * 256 + kg);
#pragma unroll
            for (int m = 0; m < 2; ++m) aro[m][n] = mfma16(a[m], b, aro[m][n]);
        }
        bf16x8 blg = ld8(W2lgT + lr * 256 + kg);
#pragma unroll
        for (int m = 0; m < 2; ++m) alg[m] = mfma16(a[m], blg, alg[m]);
    }
#pragma unroll
    for (int n = 0; n < 8; ++n) {
        int col = n * 16 + lr;
        float bia = b2ero[col];
#pragma unroll
        for (int m = 0; m < 2; ++m)
#pragma unroll
            for (int j = 0; j < 4; ++j) {
                int el = wv * 32 + m * 16 + qk * 4 + j;
                e_ro[(size_t)s_e[el] * D + col] = aro[m][n][j] + bia;
            }
    }
    if (lr < 2) {
        float bia = b2lg[lr];
#pragma unroll
        for (int m = 0; m < 2; ++m)
#pragma unroll
            for (int j = 0; j < 4; ++j) {
                int el = wv * 32 + m * 16 + qk * 4 + j;
                e_lg[(size_t)s_e[el] * 2 + lr] = alg[m][j] + bia;
            }
    }
}

// ---------------------------------------------------------------- fallback kernels (round-2 path)
__global__ void __launch_bounds__(256, 4)
edge_msg_kernel(const bf16* __restrict__ S, const bf16* __restrict__ Bm,
                const int* __restrict__ src, const int* __restrict__ dst,
                const bf16* __restrict__ We2T,
                const float* __restrict__ b_e2,
                float* __restrict__ h_out) {
    __shared__ int s_src[128];
    __shared__ int s_dst[128];
    const int t = threadIdx.x, wv = t >> 6, l = t & 63, lr = l & 15, qk = l >> 4;
    const int e0 = blockIdx.x * 128;
    if (t < 128)      s_src[t] = src[min(e0 + t, NE - 1)];
    else              s_dst[t - 128] = dst[min(e0 + t - 128, NE - 1)];
    __syncthreads();
    const bf16* pS[2];
    const bf16* pB[2];
#pragma unroll
    for (int m = 0; m < 2; ++m) {
        int el = wv * 32 + m * 16 + lr;
        pS[m] = S + s_src[el] * 256;
        pB[m] = Bm + s_dst[el] * 256;
    }
    f32x4 acc[2][8];
#pragma unroll
    for (int m = 0; m < 2; ++m)
#pragma unroll
        for (int n = 0; n < 8; ++n) acc[m][n] = 0.f;
#pragma unroll
    for (int ks = 0; ks < 8; ++ks) {
        const int kg = ks * 32 + qk * 8;
        bf16x8 a[2];
#pragma unroll
        for (int m = 0; m < 2; ++m) {
            bf16x8 sa = ld8(pS[m] + kg);
            bf16x8 sb = ld8(pB[m] + kg);
#pragma unroll
            for (int i = 0; i < 8; ++i) {
                float f = (float)sa[i] + (float)sb[i];
                a[m][i] = (bf16)(f > 0.f ? f : 0.f);
            }
        }
#pragma unroll
        for (int n = 0; n < 8; ++n) {
            bf16x8 b = ld8(We2T + (n * 16 + lr) * 256 + kg);
#pragma unroll
            for (int m = 0; m < 2; ++m) acc[m][n] = mfma16(a[m], b, acc[m][n]);
        }
    }
#pragma unroll
    for (int n = 0; n < 8; ++n) {
        int col = n * 16 + lr;
        float bia = b_e2[col];
#pragma unroll
        for (int m = 0; m < 2; ++m)
#pragma unroll
            for (int j = 0; j < 4; ++j) {
                int el = wv * 32 + m * 16 + qk * 4 + j;
                if (e0 + el < NE)
                    atomicAdd(h_out + s_dst[el] * D + col, acc[m][n][j] + bia);
            }
    }
}

__global__ void __launch_bounds__(256, 4)
edge_logit_fast(const bf16* __restrict__ U, const bf16* __restrict__ V,
                const int* __restrict__ src, const int* __restrict__ dst,
                const bf16* __restrict__ W2eroT,
                const bf16* __restrict__ W2lgT,
                const float* __restrict__ b2ero, const float* __restrict__ b2lg,
                float* __restrict__ e_ro, float* __restrict__ e_lg) {
    __shared__ int s_src[128];
    __shared__ int s_dst[128];
    const int t = threadIdx.x, wv = t >> 6, l = t & 63, lr = l & 15, qk = l >> 4;
    const int e0 = blockIdx.x * 128;
    if (t < 128)      s_src[t] = src[min(e0 + t, NE - 1)];
    else              s_dst[t - 128] = dst[min(e0 + t - 128, NE - 1)];
    __syncthreads();
    int is[2], id[2];
#pragma unroll
    for (int m = 0; m < 2; ++m) {
        int el = wv * 32 + m * 16 + lr;
        is[m] = s_src[el];
        id[m] = s_dst[el];
    }
    f32x4 aro[2][8];
    f32x4 alg[2];
#pragma unroll
    for (int m = 0; m < 2; ++m) {
        alg[m] = 0.f;
#pragma unroll
        for (int n = 0; n < 8; ++n) aro[m][n] = 0.f;
    }
#pragma unroll
    for (int ks = 0; ks < 8; ++ks) {
        const int kg = ks * 32 + qk * 8;
        bf16x8 a[2];
#pragma unroll
        for (int m = 0; m < 2; ++m) {
            bf16x8 us = ld8(U + is[m] * 256 + kg);
            bf16x8 vd = ld8(V + id[m] * 256 + kg);
            bf16x8 ud = ld8(U + id[m] * 256 + kg);
            bf16x8 vs = ld8(V + is[m] * 256 + kg);
#pragma unroll
            for (int i = 0; i < 8; ++i) {
                float f1 = (float)us[i] + (float)vd[i]; f1 = f1 > 0.f ? f1 : 0.f;
                float f2 = (float)ud[i] + (float)vs[i]; f2 = f2 > 0.f ? f2 : 0.f;
                a[m][i] = (bf16)(f1 + f2);
            }
        }
#pragma unroll
        for (int n = 0; n < 8; ++n) {
            bf16x8 b = ld8(W2eroT + (n * 16 + lr) * 256 + kg);
#pragma unroll
            for (int m = 0; m < 2; ++m) aro[m][n] = mfma16(a[m], b, aro[m][n]);
        }
        bf16x8 blg = ld8(W2lgT + lr * 256 + kg);
#pragma unroll
        for (int m = 0; m < 2; ++m) alg[m] = mfma16(a[m], blg, alg[m]);
    }
#pragma unroll
    for (int n = 0; n < 8; ++n) {
        int col = n * 16 + lr;
        float bia = b2ero[col];
#pragma unroll
        for (int m = 0; m < 2; ++m)
#pragma unroll
            for (int j = 0; j < 4; ++j) {
                int el = wv * 32 + m * 16 + qk * 4 + j;
                int e = e0 + el;
                if (e < NE) e_ro[e * D + col] = aro[m][n][j] + bia;
            }
    }
    if (lr < 2) {
        float bia = b2lg[lr];
#pragma unroll
        for (int m = 0; m < 2; ++m)
#pragma unroll
            for (int j = 0; j < 4; ++j) {
                int el = wv * 32 + m * 16 + qk * 4 + j;
                int e = e0 + el;
                if (e < NE) e_lg[e * 2 + lr] = alg[m][j] + bia;
            }
    }
}

// ---------------------------------------------------------------- n_out readout
__global__ void __launch_bounds__(256, 4)
nro_kernel(const bf16* __restrict__ nf2_bf, const bf16* __restrict__ WnroT,
           const float* __restrict__ b_nro, float* __restrict__ n_out) {
    const int r0 = blockIdx.x * 64;
    const int t = threadIdx.x, wv = t >> 6, l = t & 63, lr = l & 15, qk = l >> 4;
    int row[4];
#pragma unroll
    for (int m = 0; m < 4; ++m) { int r = r0 + m * 16 + lr; row[m] = r < NN ? r : NN - 1; }
    int col2[2];
#pragma unroll
    for (int n = 0; n < 2; ++n) col2[n] = wv * 32 + n * 16 + lr;
    f32x4 acc[4][2];
#pragma unroll
    for (int m = 0; m < 4; ++m)
#pragma unroll
        for (int n = 0; n < 2; ++n) acc[m][n] = 0.f;
#pragma unroll
    for (int ks = 0; ks < 4; ++ks) {
        const int kg = ks * 32 + qk * 8;
        bf16x8 a[4], b[2];
#pragma unroll
        for (int m = 0; m < 4; ++m) a[m] = ld8(nf2_bf + (size_t)row[m] * D + kg);
#pragma unroll
        for (int n = 0; n < 2; ++n) b[n] = ld8(WnroT + col2[n] * 128 + kg);
#pragma unroll
        for (int m = 0; m < 4; ++m)
#pragma unroll
            for (int n = 0; n < 2; ++n) acc[m][n] = mfma16(a[m], b[n], acc[m][n]);
    }
#pragma unroll
    for (int n = 0; n < 2; ++n) {
        float bia = b_nro[col2[n]];
#pragma unroll
        for (int m = 0; m < 4; ++m)
#pragma unroll
            for (int j = 0; j < 4; ++j) {
                int gr = r0 + m * 16 + qk * 4 + j;
                if (gr < NN) n_out[(size_t)gr * D + col2[n]] = acc[m][n][j] + bia;
            }
    }
}

// ---------------------------------------------------------------- launch
extern "C" void kernel_launch(void* const* d_in, const int* in_sizes, int n_in,
                              void* d_out, int out_size, void* d_ws, size_t ws_size,
                              hipStream_t stream) {
    const float* node_feat = (const float*)d_in[0];
    const int*   src   = (const int*)d_in[1];
    const int*   dst   = (const int*)d_in[2];
    const float* W_e1  = (const float*)d_in[3];
    const float* b_e1  = (const float*)d_in[4];
    const float* W_e2  = (const float*)d_in[5];
    const float* b_e2  = (const float*)d_in[6];
    const float* W_n1  = (const float*)d_in[7];
    const float* b_n1  = (const float*)d_in[8];
    const float* W_n2  = (const float*)d_in[9];
    const float* b_n2  = (const float*)d_in[10];
    const float* W_el1 = (const float*)d_in[11];
    const float* b_el1 = (const float*)d_in[12];
    const float* W_el2 = (const float*)d_in[13];
    const float* b_el2 = (const float*)d_in[14];
    const float* W_logit = (const float*)d_in[15];
    const float* b_logit = (const float*)d_in[16];
    const float* W_nro = (const float*)d_in[17];
    const float* b_nro = (const float*)d_in[18];
    const float* W_ero = (const float*)d_in[19];
    const float* b_ero = (const float*)d_in[20];

    char* ws = (char*)d_ws;
    bf16* wb = (bf16*)ws;
    bf16* WmbT   = wb;            // [512][128]
    bf16* WtopT  = wb + 65536;    // [256][128]
    bf16* We2T   = wb + 98304;    // [128][256]
    bf16* Wn1T   = wb + 131072;   // [256][256]
    bf16* Wn2T   = wb + 196608;   // [128][256]
    bf16* WuvT   = wb + 229376;   // [512][128]
    bf16* WnroT  = wb + 294912;   // [128][128]
    bf16* W2eroT = wb + 311296;   // [128][256]
    bf16* W2lgT  = wb + 344064;   // [16][256]
    float* fb    = (float*)(ws + 928000);
    float* b2ero = fb;
    float* b2lg  = fb + 128;

    float* out   = (float*)d_out;
    float* n_out = out;                 // NN*128 f32 (15.36 MB)
    float* e_ro  = out + 3840000;       // NE*128 f32 (307.2 MB)
    float* e_lg  = out + 80640000;      // NE*2 f32 (4.8 MB)

    TPack pk;
    pk.m[0]  = {W_e1 + 128 * 256, WmbT,              128, 256};
    pk.m[1]  = {W_e1 + 256 * 256, WmbT + 256 * 128,  128, 256};
    pk.m[2]  = {W_e1,             WtopT,             128, 256};
    pk.m[3]  = {W_e2,             We2T,              256, 128};
    pk.m[4]  = {W_n1,             Wn1T,              256, 256};
    pk.m[5]  = {W_n2,             Wn2T,              256, 128};
    pk.m[6]  = {W_el1,            WuvT,              128, 256};
    pk.m[7]  = {W_el1 + 128 * 256, WuvT + 256 * 128, 128, 256};
    pk.m[8]  = {W_nro,            WnroT,             128, 128};
    // slots 9-11 unused duplicates (kept so grid=12 stays valid)
    pk.m[9]  = {W_nro,            WnroT,             128, 128};
    pk.m[10] = {W_nro,            WnroT,             128, 128};
    pk.m[11] = {W_nro,            WnroT,             128, 128};

    const size_t NEED_NEW = 28888576;

    if (ws_size >= NEED_NEW) {
        // ---------------- new path: dst-sorted CSR, atomic-free ----------------
        char* eb = (char*)e_ro;   // 307.2 MB of dead-until-logit space
        bf16* S    = (bf16*)(eb);
        bf16* Bm   = (bf16*)(eb + 15360000);
        bf16* T    = (bf16*)(eb + 30720000);
        bf16* h1   = (bf16*)(eb + 46080000);
        bf16* h2   = (bf16*)(eb + 53760000);
        int* counts  = (int*)(eb + 61440000);
        int* offsets = (int*)(eb + 61560000);
        int* cursor  = (int*)(eb + 61680004);
        bf16* U    = (bf16*)n_out;           // dead until nro (runs last)
        bf16* nf2_bf = (bf16*)(ws + 1048576);
        bf16* Vbuf   = (bf16*)(ws + 8728576);
        int*  perm   = (int*)(ws + 24088576);
        u16*  srcS   = (u16*)(ws + 26488576);
        u16*  dstS   = (u16*)(ws + 27688576);

        transpose_cast_kernel<<<dim3(12, 40), 256, 0, stream>>>(pk);
        fuse_kernel<<<257, 160, 0, stream>>>(W_el2, W_ero, W_logit, b_el2, b_ero, b_logit,
                                             W2eroT, W2lgT, b2ero, b2lg);
        hipMemsetAsync(counts, 0, NN * 4, stream);
        hist_kernel<<<(NE + 255) / 256, 256, 0, stream>>>(dst, counts);
        scan_kernel<<<1, 1024, 0, stream>>>(counts, offsets, cursor);
        scatter_kernel<<<(NE + 255) / 256, 256, 0, stream>>>(src, dst, cursor,
                                                             perm, srcS, dstS);
        node_pre_kernel<false><<<dim3(469, 2), 256, 0, stream>>>(
            node_feat, nullptr, WmbT, b_e1, S, Bm);
        seg_sum_kernel<<<7500, 256, 0, stream>>>(S, Bm, offsets, srcS, T);
        h_gemm_kernel<<<469, 256, 0, stream>>>(T, We2T, b_e2, counts, h1);
        s2_update_kernel<true><<<469, 256, 0, stream>>>(h1, WtopT, S);
        seg_sum_kernel<<<7500, 256, 0, stream>>>(S, Bm, offsets, srcS, T);
        h_gemm_kernel<<<469, 256, 0, stream>>>(T, We2T, b_e2, counts, h2);
        node_mlp_kernel<true><<<469, 256, 0, stream>>>(
            node_feat, h2, Wn1T, Wn2T, b_n1, b_n2, nf2_bf);
        node_pre_kernel<true><<<dim3(469, 2), 256, 0, stream>>>(
            nullptr, nf2_bf, WuvT, b_el1, U, Vbuf);
        edge_logit_sorted<<<4688, 256, 0, stream>>>(
            U, Vbuf, perm, srcS, dstS, W2eroT, W2lgT, b2ero, b2lg, e_ro, e_lg);
        nro_kernel<<<469, 256, 0, stream>>>(nf2_bf, WnroT, b_nro, n_out);
    } else {
        // ---------------- fallback: round-2 proven path ----------------
        bf16* nf2_bf = (bf16*)(ws + 1048576);
        bf16* Vbuf   = (bf16*)(ws + 9000000);
        float* h1f = n_out;
        bf16*  S   = (bf16*)e_ro;
        bf16*  Bm  = (bf16*)((char*)e_ro + 15360000);
        float* h2f = (float*)((char*)e_ro + 30720000);
        bf16*  U   = (bf16*)n_out;

        transpose_cast_kernel<<<dim3(12, 40), 256, 0, stream>>>(pk);
        fuse_kernel<<<257, 160, 0, stream>>>(W_el2, W_ero, W_logit, b_el2, b_ero, b_logit,
                                             W2eroT, W2lgT, b2ero, b2lg);
        hipMemsetAsync(h1f, 0, (size_t)NN * D * 4, stream);
        hipMemsetAsync(h2f, 0, (size_t)NN * D * 4, stream);
        node_pre_kernel<false><<<dim3(469, 2), 256, 0, stream>>>(
            node_feat, nullptr, WmbT, b_e1, S, Bm);
        edge_msg_kernel<<<4688, 256, 0, stream>>>(S, Bm, src, dst, We2T, b_e2, h1f);
        s2_update_kernel<false><<<469, 256, 0, stream>>>(h1f, WtopT, S);
        edge_msg_kernel<<<4688, 256, 0, stream>>>(S, Bm, src, dst, We2T, b_e2, h2f);
        node_mlp_kernel<false><<<469, 256, 0, stream>>>(
            node_feat, h2f, Wn1T, Wn2T, b_n1, b_n2, nf2_bf);
        node_pre_kernel<true><<<dim3(469, 2), 256, 0, stream>>>(
            nullptr, nf2_bf, WuvT, b_el1, U, Vbuf);
        edge_logit_fast<<<4688, 256, 0, stream>>>(
            U, Vbuf, src, dst, W2eroT, W2lgT, b2ero, b2lg, e_ro, e_lg);
        nro_kernel<<<469, 256, 0, stream>>>(nf2_bf, WnroT, b_nro, n_out);
    }
}